// Round 1
// baseline (233.412 us; speedup 1.0000x reference)
//
#include <hip/hip_runtime.h>

#define FEAT 128
#define GEMM_ROWS 32

// ---------------- GEMM: P = feat @ W ; out[:, :128] = relu(P) ----------------
__global__ __launch_bounds__(256) void gemm_relu_kernel(
    const float* __restrict__ feat, const float* __restrict__ W,
    float* __restrict__ P, float* __restrict__ out, int nrows)
{
    __shared__ float sW[64 * 128];        // one half of W, k-major (32 KB)
    __shared__ float sF[GEMM_ROWS][132];  // +4 pad -> conflict-free row reads

    const int tid = threadIdx.x;
    const int rowBase = blockIdx.x * GEMM_ROWS;

    // stage feature tile (float4 coalesced)
    for (int i = tid; i < GEMM_ROWS * 32; i += 256) {
        int r = i >> 5;
        int c4 = (i & 31) << 2;
        int gr = rowBase + r;
        float4 v = make_float4(0.f, 0.f, 0.f, 0.f);
        if (gr < nrows) v = *(const float4*)&feat[(size_t)gr * FEAT + c4];
        *(float4*)&sF[r][c4] = v;
    }

    const int ct = tid & 31;   // 32 col-threads * 4 cols = 128 cols
    const int rt = tid >> 5;   // 8 row-threads  * 4 rows = 32 rows
    const int c0 = ct << 2;
    const int r0 = rt << 2;

    float acc[4][4];
    #pragma unroll
    for (int i = 0; i < 4; ++i)
        #pragma unroll
        for (int j = 0; j < 4; ++j) acc[i][j] = 0.f;

    for (int half = 0; half < 2; ++half) {
        __syncthreads();
        // stage half of W
        for (int i = tid; i < 64 * 32; i += 256) {
            int k = i >> 5;
            int c4 = (i & 31) << 2;
            *(float4*)&sW[k * 128 + c4] =
                *(const float4*)&W[(size_t)((half << 6) + k) * FEAT + c4];
        }
        __syncthreads();
        #pragma unroll 4
        for (int k = 0; k < 64; ++k) {
            float4 w = *(float4*)&sW[k * 128 + c0];
            int kk = (half << 6) + k;
            float f0 = sF[r0 + 0][kk];
            float f1 = sF[r0 + 1][kk];
            float f2 = sF[r0 + 2][kk];
            float f3 = sF[r0 + 3][kk];
            acc[0][0] += f0 * w.x; acc[0][1] += f0 * w.y; acc[0][2] += f0 * w.z; acc[0][3] += f0 * w.w;
            acc[1][0] += f1 * w.x; acc[1][1] += f1 * w.y; acc[1][2] += f1 * w.z; acc[1][3] += f1 * w.w;
            acc[2][0] += f2 * w.x; acc[2][1] += f2 * w.y; acc[2][2] += f2 * w.z; acc[2][3] += f2 * w.w;
            acc[3][0] += f3 * w.x; acc[3][1] += f3 * w.y; acc[3][2] += f3 * w.z; acc[3][3] += f3 * w.w;
        }
    }

    #pragma unroll
    for (int i = 0; i < 4; ++i) {
        int gr = rowBase + r0 + i;
        if (gr < nrows) {
            float4 v = make_float4(acc[i][0], acc[i][1], acc[i][2], acc[i][3]);
            *(float4*)&P[(size_t)gr * FEAT + c0] = v;
            float4 rl = make_float4(fmaxf(v.x, 0.f), fmaxf(v.y, 0.f),
                                    fmaxf(v.z, 0.f), fmaxf(v.w, 0.f));
            *(float4*)&out[(size_t)gr * (2 * FEAT) + c0] = rl;
        }
    }
}

// ---------------- degree count ----------------
__global__ void count_kernel(const int* __restrict__ dst, int* __restrict__ counts, int nE)
{
    int i = blockIdx.x * blockDim.x + threadIdx.x;
    if (i < nE) atomicAdd(&counts[dst[i]], 1);
}

// ---------------- hierarchical exclusive scan (chunk = 1024) ----------------
// scan_a: per-chunk local exclusive scan -> offsets (no global base), chunk totals -> blockSums
__global__ __launch_bounds__(256) void scan_a_kernel(
    const int* __restrict__ counts, int* __restrict__ offsets,
    int* __restrict__ blockSums, int n)
{
    __shared__ int waveTot[4];
    const int tid = threadIdx.x;
    const int lane = tid & 63;
    const int i0 = blockIdx.x * 1024 + tid * 4;

    int v0 = (i0 + 0 < n) ? counts[i0 + 0] : 0;
    int v1 = (i0 + 1 < n) ? counts[i0 + 1] : 0;
    int v2 = (i0 + 2 < n) ? counts[i0 + 2] : 0;
    int v3 = (i0 + 3 < n) ? counts[i0 + 3] : 0;
    int s = v0 + v1 + v2 + v3;

    // wave-level inclusive scan of s
    int incl = s;
    #pragma unroll
    for (int d = 1; d < 64; d <<= 1) {
        int t = __shfl_up(incl, d);
        if (lane >= d) incl += t;
    }
    if (lane == 63) waveTot[tid >> 6] = incl;
    __syncthreads();

    int wbase = 0;
    const int w = tid >> 6;
    for (int j = 0; j < w; ++j) wbase += waveTot[j];

    int excl = wbase + incl - s;  // exclusive over this thread's 4-group
    if (i0 + 0 < n) offsets[i0 + 0] = excl;
    if (i0 + 1 < n) offsets[i0 + 1] = excl + v0;
    if (i0 + 2 < n) offsets[i0 + 2] = excl + v0 + v1;
    if (i0 + 3 < n) offsets[i0 + 3] = excl + v0 + v1 + v2;

    if (tid == 255) blockSums[blockIdx.x] = wbase + incl;  // chunk total
}

// scan_b: exclusive scan of blockSums (nb <= 64), write grand total to *totalOut
__global__ void scan_b_kernel(int* __restrict__ blockSums, int nb, int* __restrict__ totalOut)
{
    const int lane = threadIdx.x;  // 64 threads
    int v = (lane < nb) ? blockSums[lane] : 0;
    int incl = v;
    #pragma unroll
    for (int d = 1; d < 64; d <<= 1) {
        int t = __shfl_up(incl, d);
        if (lane >= d) incl += t;
    }
    if (lane < nb) blockSums[lane] = incl - v;  // exclusive
    if (lane == 63) *totalOut = incl;           // == nE, becomes offsets[n]
}

// scan_c: add chunk base in place; also init cursor
__global__ void scan_c_kernel(int* __restrict__ offsets, const int* __restrict__ blockSums,
                              int* __restrict__ cursor, int n)
{
    int i = blockIdx.x * blockDim.x + threadIdx.x;
    if (i < n) {
        int o = offsets[i] + blockSums[i >> 10];
        offsets[i] = o;
        cursor[i] = o;
    }
}

// ---------------- CSR bucket fill ----------------
__global__ void fill_kernel(const int* __restrict__ dst, const int* __restrict__ src,
                            int* __restrict__ cursor, int* __restrict__ bucket, int nE)
{
    int i = blockIdx.x * blockDim.x + threadIdx.x;
    if (i < nE) {
        int pos = atomicAdd(&cursor[dst[i]], 1);
        bucket[pos] = src[i];
    }
}

// ---------------- per-node gather + mean + relu : out[:, 128:256] ----------------
__global__ __launch_bounds__(256) void aggregate_kernel(
    const float* __restrict__ P, const int* __restrict__ offsets,
    const int* __restrict__ bucket, float* __restrict__ out, int n)
{
    const int node = blockIdx.x * 4 + (threadIdx.x >> 6);  // one wave per node
    if (node >= n) return;
    const int lane = threadIdx.x & 63;

    const int beg = offsets[node];
    const int end = offsets[node + 1];

    float ax = 0.f, ay = 0.f;
    int j = beg;
    for (; j + 1 < end; j += 2) {
        int s0 = bucket[j];
        int s1 = bucket[j + 1];
        float2 v0 = *(const float2*)&P[(size_t)s0 * FEAT + lane * 2];
        float2 v1 = *(const float2*)&P[(size_t)s1 * FEAT + lane * 2];
        ax += v0.x + v1.x;
        ay += v0.y + v1.y;
    }
    if (j < end) {
        int s0 = bucket[j];
        float2 v0 = *(const float2*)&P[(size_t)s0 * FEAT + lane * 2];
        ax += v0.x;
        ay += v0.y;
    }

    const int deg = end - beg;
    const float inv = (deg > 0) ? (1.0f / (float)deg) : 0.0f;
    float2 r = make_float2(fmaxf(ax * inv, 0.f), fmaxf(ay * inv, 0.f));
    *(float2*)&out[(size_t)node * (2 * FEAT) + FEAT + lane * 2] = r;
}

extern "C" void kernel_launch(void* const* d_in, const int* in_sizes, int n_in,
                              void* d_out, int out_size, void* d_ws, size_t ws_size,
                              hipStream_t stream)
{
    const float* feat = (const float*)d_in[0];
    const float* W    = (const float*)d_in[1];
    const int* edst   = (const int*)d_in[2];
    const int* esrc   = (const int*)d_in[3];
    float* out        = (float*)d_out;

    const int N = in_sizes[0] / FEAT;   // 50000
    const int E = in_sizes[2];          // 640000

    // workspace layout (all 16B aligned; N*4 and E*4 are multiples of 16 here)
    char* ws = (char*)d_ws;
    float* P      = (float*)ws;                         // N*128 fp32 = 25.6 MB
    size_t off    = (size_t)N * FEAT * sizeof(float);
    int* counts   = (int*)(ws + off); off += (size_t)(N + 4) * 4;
    int* offsets  = (int*)(ws + off); off += (size_t)(N + 4) * 4;  // N+1 used
    int* cursor   = (int*)(ws + off); off += (size_t)(N + 4) * 4;
    int* bucket   = (int*)(ws + off); off += (size_t)E * 4;
    int* blockSums= (int*)(ws + off); off += 1024;

    const int nChunks = (N + 1023) / 1024;  // 49

    // 1. zero degree counts
    hipMemsetAsync(counts, 0, (size_t)N * 4, stream);

    // 2. GEMM (independent of CSR build, but stream-serial anyway)
    gemm_relu_kernel<<<(N + GEMM_ROWS - 1) / GEMM_ROWS, 256, 0, stream>>>(feat, W, P, out, N);

    // 3. degree count
    count_kernel<<<(E + 255) / 256, 256, 0, stream>>>(edst, counts, E);

    // 4-6. exclusive scan -> offsets, cursor
    scan_a_kernel<<<nChunks, 256, 0, stream>>>(counts, offsets, blockSums, N);
    scan_b_kernel<<<1, 64, 0, stream>>>(blockSums, nChunks, &offsets[N]);
    scan_c_kernel<<<(N + 255) / 256, 256, 0, stream>>>(offsets, blockSums, cursor, N);

    // 7. CSR bucket fill
    fill_kernel<<<(E + 255) / 256, 256, 0, stream>>>(edst, esrc, cursor, bucket, E);

    // 8. per-node mean of P[src] + relu
    aggregate_kernel<<<(N + 3) / 4, 256, 0, stream>>>(P, offsets, bucket, out, N);
}

// Round 2
// 226.923 us; speedup vs baseline: 1.0286x; 1.0286x over previous
//
#include <hip/hip_runtime.h>

#define FEAT 128
#define GEMM_ROWS 32

__device__ __forceinline__ float bf2f(unsigned short u) {
    return __uint_as_float(((unsigned int)u) << 16);
}
__device__ __forceinline__ unsigned short f2bf(float f) {
    unsigned int u = __float_as_uint(f);
    unsigned int r = (u + 0x7fffu + ((u >> 16) & 1u)) >> 16;  // RNE
    return (unsigned short)r;
}

// ---- GEMM: P2 = bf16(feat @ W) ; out[:, :128] = relu(feat @ W) fp32 ----
__global__ __launch_bounds__(256) void gemm_relu_kernel(
    const float* __restrict__ feat, const float* __restrict__ W,
    unsigned short* __restrict__ P2, float* __restrict__ out, int nrows)
{
    __shared__ float sW[64 * 128];        // one half of W, k-major (32 KB)
    __shared__ float sF[GEMM_ROWS][132];  // 132*4=528 B rows: 16B-aligned, pad kills conflicts

    const int tid = threadIdx.x;
    const int rowBase = blockIdx.x * GEMM_ROWS;

    for (int i = tid; i < GEMM_ROWS * 32; i += 256) {
        int r = i >> 5;
        int c4 = (i & 31) << 2;
        int gr = rowBase + r;
        float4 v = make_float4(0.f, 0.f, 0.f, 0.f);
        if (gr < nrows) v = *(const float4*)&feat[(size_t)gr * FEAT + c4];
        *(float4*)&sF[r][c4] = v;
    }

    const int ct = tid & 31;
    const int rt = tid >> 5;
    const int c0 = ct << 2;
    const int r0 = rt << 2;

    float acc[4][4];
    #pragma unroll
    for (int i = 0; i < 4; ++i)
        #pragma unroll
        for (int j = 0; j < 4; ++j) acc[i][j] = 0.f;

    for (int half = 0; half < 2; ++half) {
        __syncthreads();
        for (int i = tid; i < 64 * 32; i += 256) {
            int k = i >> 5;
            int c4 = (i & 31) << 2;
            *(float4*)&sW[k * 128 + c4] =
                *(const float4*)&W[(size_t)((half << 6) + k) * FEAT + c4];
        }
        __syncthreads();
        #pragma unroll
        for (int k4 = 0; k4 < 64; k4 += 4) {
            const int kk = (half << 6) + k4;
            float4 f[4], w[4];
            #pragma unroll
            for (int i = 0; i < 4; ++i) f[i] = *(float4*)&sF[r0 + i][kk];
            #pragma unroll
            for (int t = 0; t < 4; ++t) w[t] = *(float4*)&sW[(k4 + t) * 128 + c0];
            #pragma unroll
            for (int i = 0; i < 4; ++i) {
                acc[i][0] += f[i].x * w[0].x + f[i].y * w[1].x + f[i].z * w[2].x + f[i].w * w[3].x;
                acc[i][1] += f[i].x * w[0].y + f[i].y * w[1].y + f[i].z * w[2].y + f[i].w * w[3].y;
                acc[i][2] += f[i].x * w[0].z + f[i].y * w[1].z + f[i].z * w[2].z + f[i].w * w[3].z;
                acc[i][3] += f[i].x * w[0].w + f[i].y * w[1].w + f[i].z * w[2].w + f[i].w * w[3].w;
            }
        }
    }

    #pragma unroll
    for (int i = 0; i < 4; ++i) {
        int gr = rowBase + r0 + i;
        if (gr < nrows) {
            ushort4 p = make_ushort4(f2bf(acc[i][0]), f2bf(acc[i][1]),
                                     f2bf(acc[i][2]), f2bf(acc[i][3]));
            *(ushort4*)&P2[(size_t)gr * FEAT + c0] = p;
            float4 rl = make_float4(fmaxf(acc[i][0], 0.f), fmaxf(acc[i][1], 0.f),
                                    fmaxf(acc[i][2], 0.f), fmaxf(acc[i][3], 0.f));
            *(float4*)&out[(size_t)gr * (2 * FEAT) + c0] = rl;
        }
    }
}

// ---------------- degree count ----------------
__global__ void count_kernel(const int* __restrict__ dst, int* __restrict__ counts, int nE)
{
    int i = blockIdx.x * blockDim.x + threadIdx.x;
    if (i < nE) atomicAdd(&counts[dst[i]], 1);
}

// ---------------- hierarchical exclusive scan (chunk = 1024) ----------------
__global__ __launch_bounds__(256) void scan_a_kernel(
    const int* __restrict__ counts, int* __restrict__ offsets,
    int* __restrict__ blockSums, int n)
{
    __shared__ int waveTot[4];
    const int tid = threadIdx.x;
    const int lane = tid & 63;
    const int i0 = blockIdx.x * 1024 + tid * 4;

    int v0 = (i0 + 0 < n) ? counts[i0 + 0] : 0;
    int v1 = (i0 + 1 < n) ? counts[i0 + 1] : 0;
    int v2 = (i0 + 2 < n) ? counts[i0 + 2] : 0;
    int v3 = (i0 + 3 < n) ? counts[i0 + 3] : 0;
    int s = v0 + v1 + v2 + v3;

    int incl = s;
    #pragma unroll
    for (int d = 1; d < 64; d <<= 1) {
        int t = __shfl_up(incl, d);
        if (lane >= d) incl += t;
    }
    if (lane == 63) waveTot[tid >> 6] = incl;
    __syncthreads();

    int wbase = 0;
    const int w = tid >> 6;
    for (int j = 0; j < w; ++j) wbase += waveTot[j];

    int excl = wbase + incl - s;
    if (i0 + 0 < n) offsets[i0 + 0] = excl;
    if (i0 + 1 < n) offsets[i0 + 1] = excl + v0;
    if (i0 + 2 < n) offsets[i0 + 2] = excl + v0 + v1;
    if (i0 + 3 < n) offsets[i0 + 3] = excl + v0 + v1 + v2;

    if (tid == 255) blockSums[blockIdx.x] = wbase + incl;
}

__global__ void scan_b_kernel(int* __restrict__ blockSums, int nb, int* __restrict__ totalOut)
{
    const int lane = threadIdx.x;  // 64 threads
    int v = (lane < nb) ? blockSums[lane] : 0;
    int incl = v;
    #pragma unroll
    for (int d = 1; d < 64; d <<= 1) {
        int t = __shfl_up(incl, d);
        if (lane >= d) incl += t;
    }
    if (lane < nb) blockSums[lane] = incl - v;
    if (lane == 63) *totalOut = incl;
}

__global__ void scan_c_kernel(int* __restrict__ offsets, const int* __restrict__ blockSums,
                              int* __restrict__ cursor, int n)
{
    int i = blockIdx.x * blockDim.x + threadIdx.x;
    if (i < n) {
        int o = offsets[i] + blockSums[i >> 10];
        offsets[i] = o;
        cursor[i] = o;
    }
}

// ---------------- CSR bucket fill ----------------
__global__ void fill_kernel(const int* __restrict__ dst, const int* __restrict__ src,
                            int* __restrict__ cursor, int* __restrict__ bucket, int nE)
{
    int i = blockIdx.x * blockDim.x + threadIdx.x;
    if (i < nE) {
        int pos = atomicAdd(&cursor[dst[i]], 1);
        bucket[pos] = src[i];
    }
}

// ---- per-node mean of bf16 P2[src] + relu : out[:, 128:256] ----
// one wave per node; 2 edges per iteration; bucket indices batch-loaded
// into a register and __shfl-broadcast (no dependent index->gather chain)
__global__ __launch_bounds__(256) void aggregate_kernel(
    const unsigned short* __restrict__ P2, const int* __restrict__ offsets,
    const int* __restrict__ bucket, float* __restrict__ out, int n)
{
    const int node = blockIdx.x * 4 + (threadIdx.x >> 6);
    if (node >= n) return;
    const int lane = threadIdx.x & 63;
    const int g  = lane >> 5;   // which of the 2 edges this half-wave handles
    const int cl = lane & 31;   // features 4*cl .. 4*cl+3

    const int beg = offsets[node];
    const int end = offsets[node + 1];

    float a0 = 0.f, a1 = 0.f, a2 = 0.f, a3 = 0.f;

    for (int bs = beg; bs < end; bs += 64) {
        const int cnt = min(64, end - bs);
        int myIdx = (bs + lane < end) ? bucket[bs + lane] : 0;
        #pragma unroll 2
        for (int j = 0; j < cnt; j += 2) {
            int s = __shfl(myIdx, j + g);
            if (j + g < cnt) {
                ushort4 v = *(const ushort4*)&P2[(size_t)s * FEAT + cl * 4];
                a0 += bf2f(v.x); a1 += bf2f(v.y); a2 += bf2f(v.z); a3 += bf2f(v.w);
            }
        }
    }

    // fold the two half-wave edge-groups together
    a0 += __shfl_xor(a0, 32);
    a1 += __shfl_xor(a1, 32);
    a2 += __shfl_xor(a2, 32);
    a3 += __shfl_xor(a3, 32);

    if (g == 0) {
        const int deg = end - beg;
        const float inv = (deg > 0) ? (1.0f / (float)deg) : 0.0f;
        float4 r = make_float4(fmaxf(a0 * inv, 0.f), fmaxf(a1 * inv, 0.f),
                               fmaxf(a2 * inv, 0.f), fmaxf(a3 * inv, 0.f));
        *(float4*)&out[(size_t)node * (2 * FEAT) + FEAT + cl * 4] = r;
    }
}

extern "C" void kernel_launch(void* const* d_in, const int* in_sizes, int n_in,
                              void* d_out, int out_size, void* d_ws, size_t ws_size,
                              hipStream_t stream)
{
    const float* feat = (const float*)d_in[0];
    const float* W    = (const float*)d_in[1];
    const int* edst   = (const int*)d_in[2];
    const int* esrc   = (const int*)d_in[3];
    float* out        = (float*)d_out;

    const int N = in_sizes[0] / FEAT;   // 50000
    const int E = in_sizes[2];          // 640000

    char* ws = (char*)d_ws;
    unsigned short* P2 = (unsigned short*)ws;            // N*128 bf16 = 12.8 MB
    size_t off    = (size_t)N * FEAT * sizeof(unsigned short);
    off = (off + 15) & ~(size_t)15;
    int* counts   = (int*)(ws + off); off += (size_t)(N + 4) * 4;
    int* offsets  = (int*)(ws + off); off += (size_t)(N + 4) * 4;  // N+1 used
    int* cursor   = (int*)(ws + off); off += (size_t)(N + 4) * 4;
    int* bucket   = (int*)(ws + off); off += (size_t)E * 4;
    int* blockSums= (int*)(ws + off); off += 1024;

    const int nChunks = (N + 1023) / 1024;  // 49 (<= 64 for scan_b)

    hipMemsetAsync(counts, 0, (size_t)N * 4, stream);

    gemm_relu_kernel<<<(N + GEMM_ROWS - 1) / GEMM_ROWS, 256, 0, stream>>>(feat, W, P2, out, N);

    count_kernel<<<(E + 255) / 256, 256, 0, stream>>>(edst, counts, E);

    scan_a_kernel<<<nChunks, 256, 0, stream>>>(counts, offsets, blockSums, N);
    scan_b_kernel<<<1, 64, 0, stream>>>(blockSums, nChunks, &offsets[N]);
    scan_c_kernel<<<(N + 255) / 256, 256, 0, stream>>>(offsets, blockSums, cursor, N);

    fill_kernel<<<(E + 255) / 256, 256, 0, stream>>>(edst, esrc, cursor, bucket, E);

    aggregate_kernel<<<(N + 3) / 4, 256, 0, stream>>>(P2, offsets, bucket, out, N);
}

// Round 3
// 194.398 us; speedup vs baseline: 1.2007x; 1.1673x over previous
//
#include <hip/hip_runtime.h>

#define FEAT 128

typedef __attribute__((ext_vector_type(8))) short bhalf8;
typedef __attribute__((ext_vector_type(4))) float floatx4;

__device__ __forceinline__ float bf2f(unsigned short u) {
    return __uint_as_float(((unsigned int)u) << 16);
}
__device__ __forceinline__ unsigned short f2bf(float f) {
    unsigned int u = __float_as_uint(f);
    unsigned int r = (u + 0x7fffu + ((u >> 16) & 1u)) >> 16;  // RNE
    return (unsigned short)r;
}

// ---- W (fp32, k-major 128x128) -> Wt (bf16, n-major: Wt[n][k]) ----
__global__ void wconv_kernel(const float* __restrict__ W, unsigned short* __restrict__ Wt)
{
    int i = blockIdx.x * 256 + threadIdx.x;   // 0..16383
    int n = i >> 7;
    int k = i & 127;
    Wt[i] = f2bf(W[(size_t)k * FEAT + n]);
}

// ---- MFMA GEMM: P2 = bf16(feat @ W); out[:, :128] = relu(feat @ W) ----
// block = 256 threads = 4 waves; each wave computes 16 rows x 128 cols.
// W (bf16, transposed) staged once in LDS; A-frags loaded straight from
// global with fp32->bf16 convert (per-wave rows are private; 16 x 128B
// fully-used cache lines per K-step).
#define SB_STRIDE 136   // 128 + 8 pad shorts -> 17x16B: odd float4 stride, conflict-free
__global__ __launch_bounds__(256, 4) void gemm_mfma_kernel(
    const float* __restrict__ feat, const unsigned short* __restrict__ Wt,
    unsigned short* __restrict__ P2, float* __restrict__ out, int nrows)
{
    __shared__ unsigned short sB[128 * SB_STRIDE];  // 34816 B

    const int tid  = threadIdx.x;
    const int wave = tid >> 6;
    const int lane = tid & 63;
    const int m    = lane & 15;   // row within 16-tile (A) / col within tile (C)
    const int kg   = lane >> 4;   // k-group 0..3

    // stage Wt: 16384 shorts, 8 per iteration per thread, 16B ops
    for (int i = tid; i < 2048; i += 256) {
        int n = i >> 4;
        int k = (i & 15) << 3;
        *(uint4*)&sB[n * SB_STRIDE + k] = *(const uint4*)&Wt[(size_t)i << 3];
    }

    // load A fragments (independent of LDS staging)
    const int row  = blockIdx.x * 64 + wave * 16 + m;
    const int rowc = min(row, nrows - 1);
    bhalf8 afrag[4];
    {
        const float* ap = &feat[(size_t)rowc * FEAT + kg * 8];
        #pragma unroll
        for (int ks = 0; ks < 4; ++ks) {
            float4 f0 = *(const float4*)&ap[ks * 32];
            float4 f1 = *(const float4*)&ap[ks * 32 + 4];
            union { bhalf8 v; unsigned short u[8]; } a;
            a.u[0] = f2bf(f0.x); a.u[1] = f2bf(f0.y);
            a.u[2] = f2bf(f0.z); a.u[3] = f2bf(f0.w);
            a.u[4] = f2bf(f1.x); a.u[5] = f2bf(f1.y);
            a.u[6] = f2bf(f1.z); a.u[7] = f2bf(f1.w);
            afrag[ks] = a.v;
        }
    }

    __syncthreads();

    floatx4 acc[8];
    #pragma unroll
    for (int nt = 0; nt < 8; ++nt) acc[nt] = (floatx4){0.f, 0.f, 0.f, 0.f};

    #pragma unroll
    for (int ks = 0; ks < 4; ++ks) {
        #pragma unroll
        for (int nt = 0; nt < 8; ++nt) {
            bhalf8 b = *(bhalf8*)&sB[(nt * 16 + m) * SB_STRIDE + ks * 32 + kg * 8];
            acc[nt] = __builtin_amdgcn_mfma_f32_16x16x32_bf16(afrag[ks], b, acc[nt], 0, 0, 0);
        }
    }

    // epilogue: C/D layout col=lane&15, row=(lane>>4)*4+i
    const int rbase = blockIdx.x * 64 + wave * 16 + kg * 4;
    #pragma unroll
    for (int i = 0; i < 4; ++i) {
        int r = rbase + i;
        if (r < nrows) {
            #pragma unroll
            for (int nt = 0; nt < 8; ++nt) {
                float v = acc[nt][i];
                int c = nt * 16 + m;
                out[(size_t)r * (2 * FEAT) + c] = fmaxf(v, 0.f);
                P2[(size_t)r * FEAT + c] = f2bf(v);
            }
        }
    }
}

// ---------------- degree count (4 edges/thread) ----------------
__global__ void count_kernel(const int* __restrict__ dst, int* __restrict__ counts, int nE)
{
    int i0 = (blockIdx.x * blockDim.x + threadIdx.x) * 4;
    if (i0 + 3 < nE) {
        int4 d = *(const int4*)&dst[i0];
        atomicAdd(&counts[d.x], 1);
        atomicAdd(&counts[d.y], 1);
        atomicAdd(&counts[d.z], 1);
        atomicAdd(&counts[d.w], 1);
    } else {
        for (int i = i0; i < nE; ++i) atomicAdd(&counts[dst[i]], 1);
    }
}

// ---------------- hierarchical exclusive scan (chunk = 1024) ----------------
__global__ __launch_bounds__(256) void scan_a_kernel(
    const int* __restrict__ counts, int* __restrict__ offsets,
    int* __restrict__ blockSums, int n)
{
    __shared__ int waveTot[4];
    const int tid = threadIdx.x;
    const int lane = tid & 63;
    const int i0 = blockIdx.x * 1024 + tid * 4;

    int v0 = (i0 + 0 < n) ? counts[i0 + 0] : 0;
    int v1 = (i0 + 1 < n) ? counts[i0 + 1] : 0;
    int v2 = (i0 + 2 < n) ? counts[i0 + 2] : 0;
    int v3 = (i0 + 3 < n) ? counts[i0 + 3] : 0;
    int s = v0 + v1 + v2 + v3;

    int incl = s;
    #pragma unroll
    for (int d = 1; d < 64; d <<= 1) {
        int t = __shfl_up(incl, d);
        if (lane >= d) incl += t;
    }
    if (lane == 63) waveTot[tid >> 6] = incl;
    __syncthreads();

    int wbase = 0;
    const int w = tid >> 6;
    for (int j = 0; j < w; ++j) wbase += waveTot[j];

    int excl = wbase + incl - s;
    if (i0 + 0 < n) offsets[i0 + 0] = excl;
    if (i0 + 1 < n) offsets[i0 + 1] = excl + v0;
    if (i0 + 2 < n) offsets[i0 + 2] = excl + v0 + v1;
    if (i0 + 3 < n) offsets[i0 + 3] = excl + v0 + v1 + v2;

    if (tid == 255) blockSums[blockIdx.x] = wbase + incl;
}

__global__ void scan_b_kernel(int* __restrict__ blockSums, int nb, int* __restrict__ totalOut)
{
    const int lane = threadIdx.x;  // 64 threads
    int v = (lane < nb) ? blockSums[lane] : 0;
    int incl = v;
    #pragma unroll
    for (int d = 1; d < 64; d <<= 1) {
        int t = __shfl_up(incl, d);
        if (lane >= d) incl += t;
    }
    if (lane < nb) blockSums[lane] = incl - v;
    if (lane == 63) *totalOut = incl;
}

__global__ void scan_c_kernel(int* __restrict__ offsets, const int* __restrict__ blockSums,
                              int* __restrict__ cursor, int n)
{
    int i = blockIdx.x * blockDim.x + threadIdx.x;
    if (i < n) {
        int o = offsets[i] + blockSums[i >> 10];
        offsets[i] = o;
        cursor[i] = o;
    }
}

// ---------------- CSR bucket fill (4 edges/thread) ----------------
__global__ void fill_kernel(const int* __restrict__ dst, const int* __restrict__ src,
                            int* __restrict__ cursor, int* __restrict__ bucket, int nE)
{
    int i0 = (blockIdx.x * blockDim.x + threadIdx.x) * 4;
    if (i0 + 3 < nE) {
        int4 d = *(const int4*)&dst[i0];
        int4 s = *(const int4*)&src[i0];
        bucket[atomicAdd(&cursor[d.x], 1)] = s.x;
        bucket[atomicAdd(&cursor[d.y], 1)] = s.y;
        bucket[atomicAdd(&cursor[d.z], 1)] = s.z;
        bucket[atomicAdd(&cursor[d.w], 1)] = s.w;
    } else {
        for (int i = i0; i < nE; ++i)
            bucket[atomicAdd(&cursor[dst[i]], 1)] = src[i];
    }
}

// ---- per-node mean of bf16 P2[src] + relu : out[:, 128:256] ----
// one wave per node; 4 edges per iteration (ushort8 per lane); bucket
// indices batch-loaded and __shfl-broadcast.
__global__ __launch_bounds__(256) void aggregate_kernel(
    const unsigned short* __restrict__ P2, const int* __restrict__ offsets,
    const int* __restrict__ bucket, float* __restrict__ out, int n)
{
    const int node = blockIdx.x * 4 + (threadIdx.x >> 6);
    if (node >= n) return;
    const int lane = threadIdx.x & 63;
    const int g  = lane >> 4;   // which of 4 edges this quarter-wave handles
    const int cl = lane & 15;   // features 8*cl .. 8*cl+7

    const int beg = offsets[node];
    const int end = offsets[node + 1];

    float a[8];
    #pragma unroll
    for (int t = 0; t < 8; ++t) a[t] = 0.f;

    for (int bs = beg; bs < end; bs += 64) {
        const int cnt = min(64, end - bs);
        int myIdx = (bs + lane < end) ? bucket[bs + lane] : 0;
        #pragma unroll 2
        for (int j = 0; j < cnt; j += 4) {
            int s = __shfl(myIdx, j + g);
            if (j + g < cnt) {
                uint4 v = *(const uint4*)&P2[(size_t)s * FEAT + cl * 8];
                a[0] += __uint_as_float(v.x << 16);
                a[1] += __uint_as_float(v.x & 0xffff0000u);
                a[2] += __uint_as_float(v.y << 16);
                a[3] += __uint_as_float(v.y & 0xffff0000u);
                a[4] += __uint_as_float(v.z << 16);
                a[5] += __uint_as_float(v.z & 0xffff0000u);
                a[6] += __uint_as_float(v.w << 16);
                a[7] += __uint_as_float(v.w & 0xffff0000u);
            }
        }
    }

    // fold the 4 quarter-wave edge-groups
    #pragma unroll
    for (int t = 0; t < 8; ++t) {
        a[t] += __shfl_xor(a[t], 16);
        a[t] += __shfl_xor(a[t], 32);
    }

    if (g == 0) {
        const int deg = end - beg;
        const float inv = (deg > 0) ? (1.0f / (float)deg) : 0.0f;
        float4 r0 = make_float4(fmaxf(a[0] * inv, 0.f), fmaxf(a[1] * inv, 0.f),
                                fmaxf(a[2] * inv, 0.f), fmaxf(a[3] * inv, 0.f));
        float4 r1 = make_float4(fmaxf(a[4] * inv, 0.f), fmaxf(a[5] * inv, 0.f),
                                fmaxf(a[6] * inv, 0.f), fmaxf(a[7] * inv, 0.f));
        float* op = &out[(size_t)node * (2 * FEAT) + FEAT + cl * 8];
        *(float4*)op = r0;
        *(float4*)(op + 4) = r1;
    }
}

extern "C" void kernel_launch(void* const* d_in, const int* in_sizes, int n_in,
                              void* d_out, int out_size, void* d_ws, size_t ws_size,
                              hipStream_t stream)
{
    const float* feat = (const float*)d_in[0];
    const float* W    = (const float*)d_in[1];
    const int* edst   = (const int*)d_in[2];
    const int* esrc   = (const int*)d_in[3];
    float* out        = (float*)d_out;

    const int N = in_sizes[0] / FEAT;   // 50000
    const int E = in_sizes[2];          // 640000

    char* ws = (char*)d_ws;
    unsigned short* P2 = (unsigned short*)ws;            // N*128 bf16 = 12.8 MB
    size_t off = (size_t)N * FEAT * sizeof(unsigned short);
    off = (off + 15) & ~(size_t)15;
    unsigned short* Wt = (unsigned short*)(ws + off); off += (size_t)FEAT * FEAT * 2;
    int* counts   = (int*)(ws + off); off += (size_t)(N + 4) * 4;
    int* offsets  = (int*)(ws + off); off += (size_t)(N + 4) * 4;  // N+1 used
    int* cursor   = (int*)(ws + off); off += (size_t)(N + 4) * 4;
    int* bucket   = (int*)(ws + off); off += (size_t)E * 4;
    int* blockSums= (int*)(ws + off); off += 1024;

    const int nChunks = (N + 1023) / 1024;  // 49 (<= 64 for scan_b)

    hipMemsetAsync(counts, 0, (size_t)N * 4, stream);

    wconv_kernel<<<FEAT * FEAT / 256, 256, 0, stream>>>(W, Wt);

    gemm_mfma_kernel<<<(N + 63) / 64, 256, 0, stream>>>(feat, Wt, P2, out, N);

    count_kernel<<<(E / 4 + 255) / 256, 256, 0, stream>>>(edst, counts, E);

    scan_a_kernel<<<nChunks, 256, 0, stream>>>(counts, offsets, blockSums, N);
    scan_b_kernel<<<1, 64, 0, stream>>>(blockSums, nChunks, &offsets[N]);
    scan_c_kernel<<<(N + 255) / 256, 256, 0, stream>>>(offsets, blockSums, cursor, N);

    fill_kernel<<<(E / 4 + 255) / 256, 256, 0, stream>>>(edst, esrc, cursor, bucket, E);

    aggregate_kernel<<<(N + 3) / 4, 256, 0, stream>>>(P2, offsets, bucket, out, N);
}